// Round 10
// baseline (310.959 us; speedup 1.0000x reference)
//
#include <hip/hip_runtime.h>
#include <hip/hip_fp16.h>
#include <math.h>

#define NN 100000
#define NE 1600000
#define NF 128
#define NH 64
#define NBUCK 196     // ceil(NN / 512)
#define CHA 8192      // edges per block in partition pass
#define CAP 10240     // per-bucket capacity (mean 8163, +23 sigma)

__global__ __launch_bounds__(256) void zero_bcnt(int* bcnt) {
    int t = threadIdx.x;
    if (t < NBUCK) bcnt[t] = 0;
}

// Pass A: partition edges into 512-node dst-buckets (fixed-capacity regions).
// Packed entry: (dst & 511) << 17 | src   (src < 2^17).
__global__ __launch_bounds__(256) void part_bucket2(const int* __restrict__ src,
                                                    const int* __restrict__ dst,
                                                    int* __restrict__ bcnt,
                                                    int* __restrict__ tmp, int E) {
    __shared__ int hist[NBUCK];
    __shared__ int base[NBUCK];
    int t = threadIdx.x;
    int e0 = blockIdx.x * CHA;
    int e1 = min(e0 + CHA, E);
    if (t < NBUCK) hist[t] = 0;
    __syncthreads();
    for (int i = e0 + t; i < e1; i += 256) {
        atomicAdd(&hist[dst[i] >> 9], 1);
    }
    __syncthreads();
    if (t < NBUCK) {
        int h = hist[t];
        base[t] = h ? atomicAdd(&bcnt[t], h) : 0;
        hist[t] = 0;
    }
    __syncthreads();
    for (int i = e0 + t; i < e1; i += 256) {
        int d = dst[i];
        int b = d >> 9;
        int r = atomicAdd(&hist[b], 1);
        tmp[b * CAP + base[b] + r] = ((d & 511) << 17) | src[i];
    }
}

// exclusive scan of the 196 bucket counts -> CSR base per bucket
__global__ __launch_bounds__(256) void scan_buckets(const int* __restrict__ bcnt,
                                                    int* __restrict__ cbase,
                                                    int* __restrict__ rowptr) {
    __shared__ int s[256];
    int t = threadIdx.x;
    s[t] = (t < NBUCK) ? bcnt[t] : 0;
    __syncthreads();
    for (int off = 1; off < 256; off <<= 1) {
        int v = (t >= off) ? s[t - off] : 0;
        __syncthreads();
        s[t] += v;
        __syncthreads();
    }
    if (t < NBUCK) cbase[t] = (t == 0) ? 0 : s[t - 1];
    if (t == 0) rowptr[NN] = NE;
}

// Pass B: one block per bucket. Stage entries in LDS, per-node degree histogram
// (-> rowptr, dsq), LDS scan, LDS-cursor scatter into csr_src.
__global__ __launch_bounds__(256) void bucket_finalize(const int* __restrict__ bcnt,
                                                       const int* __restrict__ cbase,
                                                       const int* __restrict__ tmp,
                                                       int* __restrict__ rowptr,
                                                       float* __restrict__ dsq,
                                                       int* __restrict__ csr_src) {
    __shared__ int ebuf[CAP];   // 40 KB
    __shared__ int hcnt[512];
    __shared__ int hoff[512];
    __shared__ int s[256];
    int b = blockIdx.x, t = threadIdx.x;
    int cb = bcnt[b];
    int base = cbase[b];
    const int* tsrc = tmp + b * CAP;
    for (int i = t; i < cb; i += 256) ebuf[i] = tsrc[i];
    hcnt[t] = 0;
    hcnt[t + 256] = 0;
    __syncthreads();
    for (int i = t; i < cb; i += 256) atomicAdd(&hcnt[ebuf[i] >> 17], 1);
    __syncthreads();
    int c0 = hcnt[2 * t], c1 = hcnt[2 * t + 1];
    s[t] = c0 + c1;
    __syncthreads();
    for (int off = 1; off < 256; off <<= 1) {
        int v = (t >= off) ? s[t - off] : 0;
        __syncthreads();
        s[t] += v;
        __syncthreads();
    }
    int pb = (t == 0) ? 0 : s[t - 1];
    hoff[2 * t] = pb;
    hoff[2 * t + 1] = pb + c0;
    __syncthreads();
    int nodelo = b << 9;
    int nnodes = min(512, NN - nodelo);
    for (int i = t; i < nnodes; i += 256) {
        rowptr[nodelo + i] = base + hoff[i];
        dsq[nodelo + i] = rsqrtf((float)hcnt[i] + 1.0f);
    }
    __syncthreads();
    for (int i = t; i < cb; i += 256) {
        int e = ebuf[i];
        int dlow = e >> 17;
        int p = atomicAdd(&hoff[dlow], 1);
        csr_src[base + p] = e & 0x1FFFF;
    }
}

// Wc = We @ W0  [128x64], bc = be @ W0 [64]  (fold embed into layer-0 GEMM)
__global__ __launch_bounds__(256) void combine_w(const float* __restrict__ We,
                                                 const float* __restrict__ be,
                                                 const float* __restrict__ W0,
                                                 float* __restrict__ Wc,
                                                 float* __restrict__ bc) {
    __shared__ float w0[NH * NH];
    int t = threadIdx.x;
    for (int i = t; i < NH * NH; i += 256) w0[i] = W0[i];
    __syncthreads();
    int row = blockIdx.x * 4 + (t >> 6);  // We row, grid = 32
    int col = t & 63;
    float a = 0.f;
#pragma unroll 8
    for (int k = 0; k < NH; ++k) a += We[row * NH + k] * w0[k * NH + col];
    Wc[row * NH + col] = a;
    if (blockIdx.x == 0 && t < NH) {
        float s = 0.f;
        for (int k = 0; k < NH; ++k) s += be[k] * w0[k * NH + t];
        bc[t] = s;
    }
}

// hws0 = (x @ Wc + bc) * dsq[row], fp16 out.  K=128, 32 rows/block LDS-staged.
__global__ __launch_bounds__(256) void fuse0_gemm(const float* __restrict__ x,
                                                  const float* __restrict__ Wc,
                                                  const float* __restrict__ bc,
                                                  const float* __restrict__ dsq,
                                                  __half* __restrict__ hws) {
    __shared__ float tile[32 * NF];          // 16 KB
    __shared__ float red[4][32][NH];         // 32 KB
    int t = threadIdx.x;
    int lane = t & 63;
    int wave = __builtin_amdgcn_readfirstlane(t >> 6);
    int row0 = blockIdx.x * 32;

    const float4* xsrc = (const float4*)(x + (size_t)row0 * NF);
    float4* t4 = (float4*)tile;
#pragma unroll
    for (int i = 0; i < 4; ++i) t4[t + i * 256] = xsrc[t + i * 256];

    float Wreg[32];
#pragma unroll
    for (int kk = 0; kk < 32; ++kk) Wreg[kk] = Wc[(wave * 32 + kk) * NH + lane];
    __syncthreads();

    float acc[32];
#pragma unroll
    for (int r = 0; r < 32; ++r) {
        const float4* rp = (const float4*)(tile + r * NF + wave * 32);
        float a = 0.f;
#pragma unroll
        for (int q = 0; q < 8; ++q) {
            float4 v = rp[q];
            a += v.x * Wreg[q * 4 + 0];
            a += v.y * Wreg[q * 4 + 1];
            a += v.z * Wreg[q * 4 + 2];
            a += v.w * Wreg[q * 4 + 3];
        }
        acc[r] = a;
    }
#pragma unroll
    for (int r = 0; r < 32; ++r) red[wave][r][lane] = acc[r];
    __syncthreads();
#pragma unroll
    for (int i = 0; i < 8; ++i) {
        int o = i * 256 + t;
        int r = o >> 6, c = o & 63;
        float s = red[0][r][c] + red[1][r][c] + red[2][r][c] + red[3][r][c];
        int row = row0 + r;
        hws[(size_t)row * NH + c] = __float2half((s + bc[c]) * dsq[row]);
    }
}

#define GATHER_BODY                                                          \
    int t = threadIdx.x;                                                     \
    int node = blockIdx.x * 4 + (t >> 6);                                    \
    int lane = t & 63;                                                       \
    int g = lane >> 3;                                                       \
    int fl = (lane & 7) << 3;                                                \
    int beg = rowptr[node], end = rowptr[node + 1];                          \
    float a0 = 0.f, a1 = 0.f, a2 = 0.f, a3 = 0.f;                            \
    float a4 = 0.f, a5 = 0.f, a6 = 0.f, a7 = 0.f;                            \
    if (g == 0) ADDROW(node);                                                \
    int jend = beg + ((end - beg) & ~7);                                     \
    _Pragma("unroll 2") for (int j = beg; j < jend; j += 8) {                \
        int s_ = csr_src[j + g];                                             \
        ADDROW(s_);                                                          \
    }                                                                        \
    if (jend + g < end) {                                                    \
        int s_ = csr_src[jend + g];                                          \
        ADDROW(s_);                                                          \
    }                                                                        \
    a0 += __shfl_xor(a0, 8);  a1 += __shfl_xor(a1, 8);                       \
    a2 += __shfl_xor(a2, 8);  a3 += __shfl_xor(a3, 8);                       \
    a4 += __shfl_xor(a4, 8);  a5 += __shfl_xor(a5, 8);                       \
    a6 += __shfl_xor(a6, 8);  a7 += __shfl_xor(a7, 8);                       \
    a0 += __shfl_xor(a0, 16); a1 += __shfl_xor(a1, 16);                      \
    a2 += __shfl_xor(a2, 16); a3 += __shfl_xor(a3, 16);                      \
    a4 += __shfl_xor(a4, 16); a5 += __shfl_xor(a5, 16);                      \
    a6 += __shfl_xor(a6, 16); a7 += __shfl_xor(a7, 16);                      \
    a0 += __shfl_xor(a0, 32); a1 += __shfl_xor(a1, 32);                      \
    a2 += __shfl_xor(a2, 32); a3 += __shfl_xor(a3, 32);                      \
    a4 += __shfl_xor(a4, 32); a5 += __shfl_xor(a5, 32);                      \
    a6 += __shfl_xor(a6, 32); a7 += __shfl_xor(a7, 32);

#define ADDROW(sidx)                                                         \
    {                                                                        \
        uint4 rv = *(const uint4*)(hws_in + (size_t)(sidx) * NH + fl);       \
        float2 f0 = __half22float2(*(const __half2*)&rv.x);                  \
        float2 f1 = __half22float2(*(const __half2*)&rv.y);                  \
        float2 f2 = __half22float2(*(const __half2*)&rv.z);                  \
        float2 f3 = __half22float2(*(const __half2*)&rv.w);                  \
        a0 += f0.x; a1 += f0.y; a2 += f1.x; a3 += f1.y;                      \
        a4 += f2.x; a5 += f2.y; a6 += f3.x; a7 += f3.y;                      \
    }

// Fused: h = relu(dsq*(agg+self)+b); hws_out = (h @ Wn) * dsq   (fp16)
// One wave per node (4/block). Wn staged in LDS; h rows wave-private in LDS.
__global__ __launch_bounds__(256) void gather_gemm(const int* __restrict__ rowptr,
                                                   const int* __restrict__ csr_src,
                                                   const __half* __restrict__ hws_in,
                                                   const float* __restrict__ dsq,
                                                   const float* __restrict__ b,
                                                   const float* __restrict__ Wn,
                                                   __half* __restrict__ hws_out) {
    __shared__ float w_lds[NH * NH];  // 16 KB
    __shared__ float h_lds[4][NH];    // 1 KB
    {
        const float4* ws = (const float4*)Wn;
        float4* wd = (float4*)w_lds;
        int tt = threadIdx.x;
#pragma unroll
        for (int i = 0; i < 4; ++i) wd[tt + i * 256] = ws[tt + i * 256];
    }
    GATHER_BODY
    float ds = dsq[node];
    if (lane < 8) {
        float4 b0 = *(const float4*)(b + fl);
        float4 b1 = *(const float4*)(b + fl + 4);
        float4 h0, h1;
        h0.x = fmaxf(ds * a0 + b0.x, 0.f);
        h0.y = fmaxf(ds * a1 + b0.y, 0.f);
        h0.z = fmaxf(ds * a2 + b0.z, 0.f);
        h0.w = fmaxf(ds * a3 + b0.w, 0.f);
        h1.x = fmaxf(ds * a4 + b1.x, 0.f);
        h1.y = fmaxf(ds * a5 + b1.y, 0.f);
        h1.z = fmaxf(ds * a6 + b1.z, 0.f);
        h1.w = fmaxf(ds * a7 + b1.w, 0.f);
        *(float4*)&h_lds[t >> 6][fl] = h0;
        *(float4*)&h_lds[t >> 6][fl + 4] = h1;
    }
    __syncthreads();
    int r = t >> 6, c = lane;
    float acc = 0.f;
#pragma unroll
    for (int k = 0; k < NH; k += 4) {
        float4 hv = *(const float4*)&h_lds[r][k];
        acc += hv.x * w_lds[k * NH + c] + hv.y * w_lds[(k + 1) * NH + c] +
               hv.z * w_lds[(k + 2) * NH + c] + hv.w * w_lds[(k + 3) * NH + c];
    }
    hws_out[(size_t)node * NH + c] = __float2half(acc * ds);
}

// Final layer: out = relu(dsq*(agg+self)+b)  (fp32)
__global__ __launch_bounds__(256) void gather_final(const int* __restrict__ rowptr,
                                                    const int* __restrict__ csr_src,
                                                    const __half* __restrict__ hws_in,
                                                    const float* __restrict__ dsq,
                                                    const float* __restrict__ b,
                                                    float* __restrict__ outbuf) {
    GATHER_BODY
    if (lane < 8) {
        float ds = dsq[node];
        float4 b0 = *(const float4*)(b + fl);
        float4 b1 = *(const float4*)(b + fl + 4);
        float4 o0, o1;
        o0.x = fmaxf(ds * a0 + b0.x, 0.f);
        o0.y = fmaxf(ds * a1 + b0.y, 0.f);
        o0.z = fmaxf(ds * a2 + b0.z, 0.f);
        o0.w = fmaxf(ds * a3 + b0.w, 0.f);
        o1.x = fmaxf(ds * a4 + b1.x, 0.f);
        o1.y = fmaxf(ds * a5 + b1.y, 0.f);
        o1.z = fmaxf(ds * a6 + b1.z, 0.f);
        o1.w = fmaxf(ds * a7 + b1.w, 0.f);
        *(float4*)(outbuf + (size_t)node * NH + fl) = o0;
        *(float4*)(outbuf + (size_t)node * NH + fl + 4) = o1;
    }
}

extern "C" void kernel_launch(void* const* d_in, const int* in_sizes, int n_in,
                              void* d_out, int out_size, void* d_ws, size_t ws_size,
                              hipStream_t stream) {
    const float* x     = (const float*)d_in[0];
    const int*   ei    = (const int*)d_in[1];
    const float* W_emb = (const float*)d_in[2];
    const float* b_emb = (const float*)d_in[3];
    const float* Ws    = (const float*)d_in[4];
    const float* bs    = (const float*)d_in[5];
    float* out = (float*)d_out;

    const int* src = ei;
    const int* dst = ei + NE;

    char* w = (char*)d_ws;
    int*    bcnt     = (int*)w;               w += 256 * 4;
    int*    cbase    = (int*)w;               w += 256 * 4;
    int*    rowptr   = (int*)w;               w += (NN + 1) * 4;
    float*  dsq      = (float*)w;             w += NN * 4;
    float*  Wc       = (float*)w;             w += NF * NH * 4;
    float*  bc       = (float*)w;             w += NH * 4;
    int*    csr_src  = (int*)w;               w += NE * 4;
    int*    tmp      = (int*)w;               w += (size_t)NBUCK * CAP * 4;
    __half* Bh0      = (__half*)w;            w += (size_t)NN * NH * 2;
    __half* Bh1      = (__half*)w;

    // --- CSR build (once per call) ---
    zero_bcnt<<<1, 256, 0, stream>>>(bcnt);
    part_bucket2<<<(NE + CHA - 1) / CHA, 256, 0, stream>>>(src, dst, bcnt, tmp, NE);
    scan_buckets<<<1, 256, 0, stream>>>(bcnt, cbase, rowptr);
    bucket_finalize<<<NBUCK, 256, 0, stream>>>(bcnt, cbase, tmp, rowptr, dsq, csr_src);

    // --- fold embed into layer-0 weights ---
    combine_w<<<NF / 4, 256, 0, stream>>>(W_emb, b_emb, Ws, Wc, bc);

    // --- layer 0 GEMM (fused with embedding) ---
    fuse0_gemm<<<NN / 32, 256, 0, stream>>>(x, Wc, bc, dsq, Bh0);

    // --- gather0 + layer1 GEMM fused ---
    gather_gemm<<<NN / 4, 256, 0, stream>>>(rowptr, csr_src, Bh0, dsq, bs,
                                            Ws + 1 * NH * NH, Bh1);
    // --- gather1 + layer2 GEMM fused ---
    gather_gemm<<<NN / 4, 256, 0, stream>>>(rowptr, csr_src, Bh1, dsq, bs + NH,
                                            Ws + 2 * NH * NH, Bh0);
    // --- final gather ---
    gather_final<<<NN / 4, 256, 0, stream>>>(rowptr, csr_src, Bh0, dsq,
                                             bs + 2 * NH, out);
}

// Round 11
// 296.387 us; speedup vs baseline: 1.0492x; 1.0492x over previous
//
#include <hip/hip_runtime.h>
#include <hip/hip_fp16.h>
#include <math.h>

#define NN 100000
#define NE 1600000
#define NF 128
#define NH 64
#define NBUCK 196     // ceil(NN / 512)
#define CHA 8192      // edges per block in partition pass
#define CAP 10240     // per-bucket capacity (mean 8163, +23 sigma)

// Pass A: partition edges into 512-node dst-buckets (fixed-capacity regions).
// Packed entry: (dst & 511) << 17 | src   (src < 2^17).
__global__ __launch_bounds__(256) void part_bucket2(const int* __restrict__ src,
                                                    const int* __restrict__ dst,
                                                    int* __restrict__ bcnt,
                                                    int* __restrict__ tmp, int E) {
    __shared__ int hist[NBUCK];
    __shared__ int base[NBUCK];
    int t = threadIdx.x;
    int e0 = blockIdx.x * CHA;
    int e1 = min(e0 + CHA, E);
    if (t < NBUCK) hist[t] = 0;
    __syncthreads();
    for (int i = e0 + t; i < e1; i += 256) {
        atomicAdd(&hist[dst[i] >> 9], 1);
    }
    __syncthreads();
    if (t < NBUCK) {
        int h = hist[t];
        base[t] = h ? atomicAdd(&bcnt[t], h) : 0;
        hist[t] = 0;
    }
    __syncthreads();
    for (int i = e0 + t; i < e1; i += 256) {
        int d = dst[i];
        int b = d >> 9;
        int r = atomicAdd(&hist[b], 1);
        tmp[b * CAP + base[b] + r] = ((d & 511) << 17) | src[i];
    }
}

// exclusive scan of the 196 bucket counts -> CSR base per bucket
__global__ __launch_bounds__(256) void scan_buckets(const int* __restrict__ bcnt,
                                                    int* __restrict__ cbase,
                                                    int* __restrict__ rowptr) {
    __shared__ int s[256];
    int t = threadIdx.x;
    s[t] = (t < NBUCK) ? bcnt[t] : 0;
    __syncthreads();
    for (int off = 1; off < 256; off <<= 1) {
        int v = (t >= off) ? s[t - off] : 0;
        __syncthreads();
        s[t] += v;
        __syncthreads();
    }
    if (t < NBUCK) cbase[t] = (t == 0) ? 0 : s[t - 1];
    if (t == 0) rowptr[NN] = NE;
}

// Pass B: one block per bucket. Stage entries in LDS, per-node degree histogram
// (-> rowptr, dsq), LDS scan, LDS-cursor scatter into csr_src.
__global__ __launch_bounds__(256) void bucket_finalize(const int* __restrict__ bcnt,
                                                       const int* __restrict__ cbase,
                                                       const int* __restrict__ tmp,
                                                       int* __restrict__ rowptr,
                                                       float* __restrict__ dsq,
                                                       int* __restrict__ csr_src) {
    __shared__ int ebuf[CAP];   // 40 KB
    __shared__ int hcnt[512];
    __shared__ int hoff[512];
    __shared__ int s[256];
    int b = blockIdx.x, t = threadIdx.x;
    int cb = bcnt[b];
    int base = cbase[b];
    const int* tsrc = tmp + b * CAP;
    for (int i = t; i < cb; i += 256) ebuf[i] = tsrc[i];
    hcnt[t] = 0;
    hcnt[t + 256] = 0;
    __syncthreads();
    for (int i = t; i < cb; i += 256) atomicAdd(&hcnt[ebuf[i] >> 17], 1);
    __syncthreads();
    int c0 = hcnt[2 * t], c1 = hcnt[2 * t + 1];
    s[t] = c0 + c1;
    __syncthreads();
    for (int off = 1; off < 256; off <<= 1) {
        int v = (t >= off) ? s[t - off] : 0;
        __syncthreads();
        s[t] += v;
        __syncthreads();
    }
    int pb = (t == 0) ? 0 : s[t - 1];
    hoff[2 * t] = pb;
    hoff[2 * t + 1] = pb + c0;
    __syncthreads();
    int nodelo = b << 9;
    int nnodes = min(512, NN - nodelo);
    for (int i = t; i < nnodes; i += 256) {
        rowptr[nodelo + i] = base + hoff[i];
        dsq[nodelo + i] = rsqrtf((float)hcnt[i] + 1.0f);
    }
    __syncthreads();
    for (int i = t; i < cb; i += 256) {
        int e = ebuf[i];
        int dlow = e >> 17;
        int p = atomicAdd(&hoff[dlow], 1);
        csr_src[base + p] = e & 0x1FFFF;
    }
}

// Wc = We @ W0  [128x64], bc = be @ W0 [64]  (fold embed into layer-0 GEMM)
__global__ __launch_bounds__(256) void combine_w(const float* __restrict__ We,
                                                 const float* __restrict__ be,
                                                 const float* __restrict__ W0,
                                                 float* __restrict__ Wc,
                                                 float* __restrict__ bc) {
    __shared__ float w0[NH * NH];
    int t = threadIdx.x;
    for (int i = t; i < NH * NH; i += 256) w0[i] = W0[i];
    __syncthreads();
    int row = blockIdx.x * 4 + (t >> 6);  // We row, grid = 32
    int col = t & 63;
    float a = 0.f;
#pragma unroll 8
    for (int k = 0; k < NH; ++k) a += We[row * NH + k] * w0[k * NH + col];
    Wc[row * NH + col] = a;
    if (blockIdx.x == 0 && t < NH) {
        float s = 0.f;
        for (int k = 0; k < NH; ++k) s += be[k] * w0[k * NH + t];
        bc[t] = s;
    }
}

// hws0 = (x @ Wc + bc) * dsq[row], fp16 out.  K=128, 16 rows/block LDS-staged.
__global__ __launch_bounds__(256) void fuse0_gemm(const float* __restrict__ x,
                                                  const float* __restrict__ Wc,
                                                  const float* __restrict__ bc,
                                                  const float* __restrict__ dsq,
                                                  __half* __restrict__ hws) {
    __shared__ float tile[16 * NF];          // 8 KB
    __shared__ float red[4][16][NH];         // 16 KB
    int t = threadIdx.x;
    int lane = t & 63;
    int wave = __builtin_amdgcn_readfirstlane(t >> 6);
    int row0 = blockIdx.x * 16;

    const float4* xsrc = (const float4*)(x + (size_t)row0 * NF);
    float4* t4 = (float4*)tile;
    t4[t] = xsrc[t];
    t4[t + 256] = xsrc[t + 256];

    float Wreg[32];
#pragma unroll
    for (int kk = 0; kk < 32; ++kk) Wreg[kk] = Wc[(wave * 32 + kk) * NH + lane];
    __syncthreads();

    float acc[16];
#pragma unroll
    for (int r = 0; r < 16; ++r) {
        const float4* rp = (const float4*)(tile + r * NF + wave * 32);
        float a = 0.f;
#pragma unroll
        for (int q = 0; q < 8; ++q) {
            float4 v = rp[q];
            a += v.x * Wreg[q * 4 + 0];
            a += v.y * Wreg[q * 4 + 1];
            a += v.z * Wreg[q * 4 + 2];
            a += v.w * Wreg[q * 4 + 3];
        }
        acc[r] = a;
    }
#pragma unroll
    for (int r = 0; r < 16; ++r) red[wave][r][lane] = acc[r];
    __syncthreads();
#pragma unroll
    for (int i = 0; i < 4; ++i) {
        int o = i * 256 + t;
        int r = o >> 6, c = o & 63;
        float s = red[0][r][c] + red[1][r][c] + red[2][r][c] + red[3][r][c];
        int row = row0 + r;
        hws[(size_t)row * NH + c] = __float2half((s + bc[c]) * dsq[row]);
    }
}

// hws = (h @ W) * dsq[row], fp16 in/out.  K=64, LDS-staged h tile.
__global__ __launch_bounds__(256) void layer_gemm(const __half* __restrict__ h,
                                                  const float* __restrict__ W,
                                                  const float* __restrict__ dsq,
                                                  __half* __restrict__ hws) {
    __shared__ float tile[16 * NH];          // 4 KB
    __shared__ float red[4][16][NH];         // 16 KB
    int t = threadIdx.x;
    int lane = t & 63;
    int wave = __builtin_amdgcn_readfirstlane(t >> 6);
    int row0 = blockIdx.x * 16;

    {   // stage 1024 fp16 -> fp32 LDS; 4 halves (8B) per thread
        uint2 v = ((const uint2*)(h + (size_t)row0 * NH))[t];
        float2 p0 = __half22float2(*(const __half2*)&v.x);
        float2 p1 = __half22float2(*(const __half2*)&v.y);
        float4 f = make_float4(p0.x, p0.y, p1.x, p1.y);
        *(float4*)&tile[t * 4] = f;
    }

    float Wreg[16];
#pragma unroll
    for (int kk = 0; kk < 16; ++kk) Wreg[kk] = W[(wave * 16 + kk) * NH + lane];
    __syncthreads();

    float acc[16];
#pragma unroll
    for (int r = 0; r < 16; ++r) {
        const float4* rp = (const float4*)(tile + r * NH + wave * 16);
        float a = 0.f;
#pragma unroll
        for (int q = 0; q < 4; ++q) {
            float4 v = rp[q];
            a += v.x * Wreg[q * 4 + 0];
            a += v.y * Wreg[q * 4 + 1];
            a += v.z * Wreg[q * 4 + 2];
            a += v.w * Wreg[q * 4 + 3];
        }
        acc[r] = a;
    }
#pragma unroll
    for (int r = 0; r < 16; ++r) red[wave][r][lane] = acc[r];
    __syncthreads();
#pragma unroll
    for (int i = 0; i < 4; ++i) {
        int o = i * 256 + t;
        int r = o >> 6, c = o & 63;
        float s = red[0][r][c] + red[1][r][c] + red[2][r][c] + red[3][r][c];
        int row = row0 + r;
        hws[(size_t)row * NH + c] = __float2half(s * dsq[row]);
    }
}

// Gather core: wave per node, 8 groups of 8 lanes; 64 edge indices loaded with
// ONE coalesced read, broadcast via shfl -> row loads have no index dependency
// and issue back-to-back (8 in flight). Partial steps clamp to deg-1 + mask.
#define ADDROWM(sidx, m)                                                     \
    {                                                                        \
        uint4 rv = *(const uint4*)(hws_in + (size_t)(sidx) * NH + fl);       \
        float2 f0 = __half22float2(*(const __half2*)&rv.x);                  \
        float2 f1 = __half22float2(*(const __half2*)&rv.y);                  \
        float2 f2 = __half22float2(*(const __half2*)&rv.z);                  \
        float2 f3 = __half22float2(*(const __half2*)&rv.w);                  \
        a0 += f0.x * (m); a1 += f0.y * (m); a2 += f1.x * (m); a3 += f1.y * (m); \
        a4 += f2.x * (m); a5 += f2.y * (m); a6 += f3.x * (m); a7 += f3.y * (m); \
    }

#define GATHER_BODY                                                          \
    int t = threadIdx.x;                                                     \
    int node = blockIdx.x * 4 + (t >> 6);                                    \
    int lane = t & 63;                                                       \
    int g = lane >> 3;                                                       \
    int fl = (lane & 7) << 3;                                                \
    int beg = rowptr[node], end = rowptr[node + 1];                          \
    int deg = end - beg;                                                     \
    float a0 = 0.f, a1 = 0.f, a2 = 0.f, a3 = 0.f;                            \
    float a4 = 0.f, a5 = 0.f, a6 = 0.f, a7 = 0.f;                            \
    if (g == 0) ADDROWM(node, 1.f);                                          \
    int idxl = csr_src[min(beg + lane, NE - 1)];                             \
    _Pragma("unroll")                                                        \
    for (int k = 0; k < 8; ++k) {                                            \
        if (k * 8 < deg) {                                                   \
            int e = k * 8 + g;                                               \
            int s_ = __shfl(idxl, min(e, deg - 1));                          \
            float m = (e < deg) ? 1.f : 0.f;                                 \
            ADDROWM(s_, m);                                                  \
        }                                                                    \
    }                                                                        \
    for (int jb = beg + 64; jb < end; jb += 64) {  /* deg>64 fallback */     \
        int rem = end - jb;                                                  \
        int idx2 = csr_src[min(jb + lane, NE - 1)];                          \
        _Pragma("unroll")                                                    \
        for (int k = 0; k < 8; ++k) {                                        \
            if (k * 8 < rem) {                                               \
                int e = k * 8 + g;                                           \
                int s_ = __shfl(idx2, min(e, rem - 1));                      \
                float m = (e < rem) ? 1.f : 0.f;                             \
                ADDROWM(s_, m);                                              \
            }                                                                \
        }                                                                    \
    }                                                                        \
    a0 += __shfl_xor(a0, 8);  a1 += __shfl_xor(a1, 8);                       \
    a2 += __shfl_xor(a2, 8);  a3 += __shfl_xor(a3, 8);                       \
    a4 += __shfl_xor(a4, 8);  a5 += __shfl_xor(a5, 8);                       \
    a6 += __shfl_xor(a6, 8);  a7 += __shfl_xor(a7, 8);                       \
    a0 += __shfl_xor(a0, 16); a1 += __shfl_xor(a1, 16);                      \
    a2 += __shfl_xor(a2, 16); a3 += __shfl_xor(a3, 16);                      \
    a4 += __shfl_xor(a4, 16); a5 += __shfl_xor(a5, 16);                      \
    a6 += __shfl_xor(a6, 16); a7 += __shfl_xor(a7, 16);                      \
    a0 += __shfl_xor(a0, 32); a1 += __shfl_xor(a1, 32);                      \
    a2 += __shfl_xor(a2, 32); a3 += __shfl_xor(a3, 32);                      \
    a4 += __shfl_xor(a4, 32); a5 += __shfl_xor(a5, 32);                      \
    a6 += __shfl_xor(a6, 32); a7 += __shfl_xor(a7, 32);

// h = relu(dsq*(agg+self)+b), fp16 out (feeds layer_gemm)
__global__ __launch_bounds__(256) void gather_h(const int* __restrict__ rowptr,
                                                const int* __restrict__ csr_src,
                                                const __half* __restrict__ hws_in,
                                                const float* __restrict__ dsq,
                                                const float* __restrict__ b,
                                                __half* __restrict__ hout) {
    GATHER_BODY
    if (lane < 8) {
        float ds = dsq[node];
        float4 b0 = *(const float4*)(b + fl);
        float4 b1 = *(const float4*)(b + fl + 4);
        __half2 o[4];
        o[0] = __floats2half2_rn(fmaxf(ds * a0 + b0.x, 0.f), fmaxf(ds * a1 + b0.y, 0.f));
        o[1] = __floats2half2_rn(fmaxf(ds * a2 + b0.z, 0.f), fmaxf(ds * a3 + b0.w, 0.f));
        o[2] = __floats2half2_rn(fmaxf(ds * a4 + b1.x, 0.f), fmaxf(ds * a5 + b1.y, 0.f));
        o[3] = __floats2half2_rn(fmaxf(ds * a6 + b1.z, 0.f), fmaxf(ds * a7 + b1.w, 0.f));
        *(uint4*)(hout + (size_t)node * NH + fl) = *(const uint4*)o;
    }
}

// final: out = relu(dsq*(agg+self)+b), fp32
__global__ __launch_bounds__(256) void gather_out(const int* __restrict__ rowptr,
                                                  const int* __restrict__ csr_src,
                                                  const __half* __restrict__ hws_in,
                                                  const float* __restrict__ dsq,
                                                  const float* __restrict__ b,
                                                  float* __restrict__ outbuf) {
    GATHER_BODY
    if (lane < 8) {
        float ds = dsq[node];
        float4 b0 = *(const float4*)(b + fl);
        float4 b1 = *(const float4*)(b + fl + 4);
        float4 o0, o1;
        o0.x = fmaxf(ds * a0 + b0.x, 0.f);
        o0.y = fmaxf(ds * a1 + b0.y, 0.f);
        o0.z = fmaxf(ds * a2 + b0.z, 0.f);
        o0.w = fmaxf(ds * a3 + b0.w, 0.f);
        o1.x = fmaxf(ds * a4 + b1.x, 0.f);
        o1.y = fmaxf(ds * a5 + b1.y, 0.f);
        o1.z = fmaxf(ds * a6 + b1.z, 0.f);
        o1.w = fmaxf(ds * a7 + b1.w, 0.f);
        *(float4*)(outbuf + (size_t)node * NH + fl) = o0;
        *(float4*)(outbuf + (size_t)node * NH + fl + 4) = o1;
    }
}

extern "C" void kernel_launch(void* const* d_in, const int* in_sizes, int n_in,
                              void* d_out, int out_size, void* d_ws, size_t ws_size,
                              hipStream_t stream) {
    const float* x     = (const float*)d_in[0];
    const int*   ei    = (const int*)d_in[1];
    const float* W_emb = (const float*)d_in[2];
    const float* b_emb = (const float*)d_in[3];
    const float* Ws    = (const float*)d_in[4];
    const float* bs    = (const float*)d_in[5];
    float* out = (float*)d_out;

    const int* src = ei;
    const int* dst = ei + NE;

    char* w = (char*)d_ws;
    int*    bcnt     = (int*)w;               w += 256 * 4;
    int*    cbase    = (int*)w;               w += 256 * 4;
    int*    rowptr   = (int*)w;               w += (NN + 1) * 4;
    float*  dsq      = (float*)w;             w += NN * 4;
    float*  Wc       = (float*)w;             w += NF * NH * 4;
    float*  bc       = (float*)w;             w += NH * 4;
    int*    csr_src  = (int*)w;               w += NE * 4;
    int*    tmp      = (int*)w;               w += (size_t)NBUCK * CAP * 4;
    __half* Bh       = (__half*)w;            w += (size_t)NN * NH * 2;   // hws
    __half* H16      = (__half*)w;                                       // h

    // --- CSR build (once per call) ---
    hipMemsetAsync(bcnt, 0, 256 * 4, stream);
    part_bucket2<<<(NE + CHA - 1) / CHA, 256, 0, stream>>>(src, dst, bcnt, tmp, NE);
    scan_buckets<<<1, 256, 0, stream>>>(bcnt, cbase, rowptr);
    bucket_finalize<<<NBUCK, 256, 0, stream>>>(bcnt, cbase, tmp, rowptr, dsq, csr_src);

    // --- fold embed into layer-0 weights ---
    combine_w<<<NF / 4, 256, 0, stream>>>(W_emb, b_emb, Ws, Wc, bc);

    // --- layer 0 GEMM (fused with embedding) ---
    fuse0_gemm<<<NN / 16, 256, 0, stream>>>(x, Wc, bc, dsq, Bh);

    // --- layer 0 gather -> h ; layer 1 GEMM ; gather -> h ; layer 2 GEMM ---
    gather_h<<<NN / 4, 256, 0, stream>>>(rowptr, csr_src, Bh, dsq, bs, H16);
    layer_gemm<<<NN / 16, 256, 0, stream>>>(H16, Ws + 1 * NH * NH, dsq, Bh);
    gather_h<<<NN / 4, 256, 0, stream>>>(rowptr, csr_src, Bh, dsq, bs + NH, H16);
    layer_gemm<<<NN / 16, 256, 0, stream>>>(H16, Ws + 2 * NH * NH, dsq, Bh);
    // --- final gather ---
    gather_out<<<NN / 4, 256, 0, stream>>>(rowptr, csr_src, Bh, dsq,
                                           bs + 2 * NH, out);
}

// Round 12
// 280.733 us; speedup vs baseline: 1.1077x; 1.0558x over previous
//
#include <hip/hip_runtime.h>
#include <hip/hip_fp16.h>
#include <math.h>

#define NN 100000
#define NE 1600000
#define NF 128
#define NH 64
#define NBUCK 196     // ceil(NN / 512)
#define CHA 8192      // edges per block in partition pass
#define CAP 10240     // per-bucket capacity (mean 8163, +23 sigma)
#define NBLK 1563     // ceil(NN / 64) for MFMA GEMMs

typedef _Float16 f16x8 __attribute__((ext_vector_type(8)));
typedef float f32x4 __attribute__((ext_vector_type(4)));

// Pass A: partition edges into 512-node dst-buckets (fixed-capacity regions).
// Packed entry: (dst & 511) << 17 | src   (src < 2^17).
__global__ __launch_bounds__(256) void part_bucket2(const int* __restrict__ src,
                                                    const int* __restrict__ dst,
                                                    int* __restrict__ bcnt,
                                                    int* __restrict__ tmp, int E) {
    __shared__ int hist[NBUCK];
    __shared__ int base[NBUCK];
    int t = threadIdx.x;
    int e0 = blockIdx.x * CHA;
    int e1 = min(e0 + CHA, E);
    if (t < NBUCK) hist[t] = 0;
    __syncthreads();
    for (int i = e0 + t; i < e1; i += 256) {
        atomicAdd(&hist[dst[i] >> 9], 1);
    }
    __syncthreads();
    if (t < NBUCK) {
        int h = hist[t];
        base[t] = h ? atomicAdd(&bcnt[t], h) : 0;
        hist[t] = 0;
    }
    __syncthreads();
    for (int i = e0 + t; i < e1; i += 256) {
        int d = dst[i];
        int b = d >> 9;
        int r = atomicAdd(&hist[b], 1);
        tmp[b * CAP + base[b] + r] = ((d & 511) << 17) | src[i];
    }
}

// exclusive scan of the 196 bucket counts -> CSR base per bucket
__global__ __launch_bounds__(256) void scan_buckets(const int* __restrict__ bcnt,
                                                    int* __restrict__ cbase,
                                                    int* __restrict__ rowptr) {
    __shared__ int s[256];
    int t = threadIdx.x;
    s[t] = (t < NBUCK) ? bcnt[t] : 0;
    __syncthreads();
    for (int off = 1; off < 256; off <<= 1) {
        int v = (t >= off) ? s[t - off] : 0;
        __syncthreads();
        s[t] += v;
        __syncthreads();
    }
    if (t < NBUCK) cbase[t] = (t == 0) ? 0 : s[t - 1];
    if (t == 0) rowptr[NN] = NE;
}

// Pass B: one block per bucket. Stage entries in LDS, per-node degree histogram
// (-> rowptr, dsq), LDS scan, LDS-cursor scatter into csr_src.
__global__ __launch_bounds__(256) void bucket_finalize(const int* __restrict__ bcnt,
                                                       const int* __restrict__ cbase,
                                                       const int* __restrict__ tmp,
                                                       int* __restrict__ rowptr,
                                                       float* __restrict__ dsq,
                                                       int* __restrict__ csr_src) {
    __shared__ int ebuf[CAP];   // 40 KB
    __shared__ int hcnt[512];
    __shared__ int hoff[512];
    __shared__ int s[256];
    int b = blockIdx.x, t = threadIdx.x;
    int cb = bcnt[b];
    int base = cbase[b];
    const int* tsrc = tmp + b * CAP;
    for (int i = t; i < cb; i += 256) ebuf[i] = tsrc[i];
    hcnt[t] = 0;
    hcnt[t + 256] = 0;
    __syncthreads();
    for (int i = t; i < cb; i += 256) atomicAdd(&hcnt[ebuf[i] >> 17], 1);
    __syncthreads();
    int c0 = hcnt[2 * t], c1 = hcnt[2 * t + 1];
    s[t] = c0 + c1;
    __syncthreads();
    for (int off = 1; off < 256; off <<= 1) {
        int v = (t >= off) ? s[t - off] : 0;
        __syncthreads();
        s[t] += v;
        __syncthreads();
    }
    int pb = (t == 0) ? 0 : s[t - 1];
    hoff[2 * t] = pb;
    hoff[2 * t + 1] = pb + c0;
    __syncthreads();
    int nodelo = b << 9;
    int nnodes = min(512, NN - nodelo);
    for (int i = t; i < nnodes; i += 256) {
        rowptr[nodelo + i] = base + hoff[i];
        dsq[nodelo + i] = rsqrtf((float)hcnt[i] + 1.0f);
    }
    __syncthreads();
    for (int i = t; i < cb; i += 256) {
        int e = ebuf[i];
        int dlow = e >> 17;
        int p = atomicAdd(&hoff[dlow], 1);
        csr_src[base + p] = e & 0x1FFFF;
    }
}

// Wct[col][k] = (We @ W0)^T in fp16 (128 k x 64 col source), bc = be @ W0
__global__ __launch_bounds__(256) void combine_w(const float* __restrict__ We,
                                                 const float* __restrict__ be,
                                                 const float* __restrict__ W0,
                                                 _Float16* __restrict__ Wct,
                                                 float* __restrict__ bc) {
    __shared__ float w0[NH * NH];
    int t = threadIdx.x;
    for (int i = t; i < NH * NH; i += 256) w0[i] = W0[i];
    __syncthreads();
    int row = blockIdx.x * 4 + (t >> 6);  // k index 0..127, grid = 32
    int col = t & 63;
    float a = 0.f;
#pragma unroll 8
    for (int k = 0; k < NH; ++k) a += We[row * NH + k] * w0[k * NH + col];
    Wct[col * NF + row] = (_Float16)a;
    if (blockIdx.x == 0 && t < NH) {
        float s = 0.f;
        for (int k = 0; k < NH; ++k) s += be[k] * w0[k * NH + t];
        bc[t] = s;
    }
}

// Wt[col][k] = W^T fp16  (W is [64][64] fp32). grid 16 x 256.
__global__ __launch_bounds__(256) void wconv(const float* __restrict__ W,
                                             _Float16* __restrict__ Wt) {
    int i = blockIdx.x * 256 + threadIdx.x;  // 4096
    int k = i >> 6, c = i & 63;
    Wt[c * NH + k] = (_Float16)W[i];
}

// hws0 = (x @ Wc + bc) * dsq[row], fp16 out. MFMA 16x16x32_f16, 64 rows/block.
__global__ __launch_bounds__(256) void fuse0_gemm(const float* __restrict__ x,
                                                  const _Float16* __restrict__ Wct,
                                                  const float* __restrict__ bc,
                                                  const float* __restrict__ dsq,
                                                  __half* __restrict__ hws) {
    __shared__ _Float16 sh[64 * NF];  // 16 KB, 256B rows, XOR-swizzled
    int t = threadIdx.x;
    int lane = t & 63;
    int w = t >> 6;
    int row0 = blockIdx.x * 64;

    // B fragments: bf[ct][ks], col = ct*16+(l&15), k = ks*32+(l>>4)*8
    f16x8 bf[4][4];
#pragma unroll
    for (int ct = 0; ct < 4; ++ct)
#pragma unroll
        for (int ks = 0; ks < 4; ++ks) {
            int col = ct * 16 + (lane & 15);
            int k = ks * 32 + (lane >> 4) * 8;
            bf[ct][ks] = *(const f16x8*)(Wct + col * NF + k);
        }

    // stage x tile (fp32 -> fp16), 8 float4 per thread
    const float4* xs = (const float4*)x;
#pragma unroll
    for (int i = 0; i < 8; ++i) {
        int f = t + i * 256;
        int r = f >> 5;       // 32 float4 per row
        int c4 = f & 31;
        int row = min(row0 + r, NN - 1);
        float4 v = xs[(size_t)row * 32 + c4];
        __half2 h0 = __floats2half2_rn(v.x, v.y);
        __half2 h1 = __floats2half2_rn(v.z, v.w);
        uint2 u;
        u.x = *(unsigned*)&h0;
        u.y = *(unsigned*)&h1;
        int byte = (r * 256 + c4 * 8) ^ ((r & 7) << 4);
        *(uint2*)((char*)sh + byte) = u;
    }
    __syncthreads();

    f32x4 acc[4] = {{0.f, 0.f, 0.f, 0.f}, {0.f, 0.f, 0.f, 0.f},
                    {0.f, 0.f, 0.f, 0.f}, {0.f, 0.f, 0.f, 0.f}};
    int ar = w * 16 + (lane & 15);
    int ak = (lane >> 4) * 8;
#pragma unroll
    for (int ks = 0; ks < 4; ++ks) {
        int byte = (ar * 256 + (ks * 32 + ak) * 2) ^ ((ar & 7) << 4);
        f16x8 af = *(const f16x8*)((const char*)sh + byte);
#pragma unroll
        for (int ct = 0; ct < 4; ++ct)
            acc[ct] = __builtin_amdgcn_mfma_f32_16x16x32_f16(af, bf[ct][ks], acc[ct], 0, 0, 0);
    }
#pragma unroll
    for (int ct = 0; ct < 4; ++ct) {
        int col = ct * 16 + (lane & 15);
        float bcv = bc[col];
#pragma unroll
        for (int r2 = 0; r2 < 4; ++r2) {
            int row = row0 + w * 16 + (lane >> 4) * 4 + r2;
            if (row < NN)
                hws[(size_t)row * NH + col] = __float2half((acc[ct][r2] + bcv) * dsq[row]);
        }
    }
}

// hws = (h @ W) * dsq[row], fp16 in/out. MFMA, K=64, 64 rows/block.
__global__ __launch_bounds__(256) void layer_gemm(const __half* __restrict__ h,
                                                  const _Float16* __restrict__ Wt,
                                                  const float* __restrict__ dsq,
                                                  __half* __restrict__ hws) {
    __shared__ _Float16 sh[64 * NH];  // 8 KB, 128B rows, XOR-swizzled
    int t = threadIdx.x;
    int lane = t & 63;
    int w = t >> 6;
    int row0 = blockIdx.x * 64;

    f16x8 bf[4][2];
#pragma unroll
    for (int ct = 0; ct < 4; ++ct)
#pragma unroll
        for (int ks = 0; ks < 2; ++ks) {
            int col = ct * 16 + (lane & 15);
            int k = ks * 32 + (lane >> 4) * 8;
            bf[ct][ks] = *(const f16x8*)(Wt + col * NH + k);
        }

#pragma unroll
    for (int i = 0; i < 2; ++i) {
        int u = t + i * 256;
        int r = u >> 3;       // 8 uint4 per row
        int c8 = u & 7;
        int row = min(row0 + r, NN - 1);
        uint4 v = *(const uint4*)(h + (size_t)row * NH + c8 * 8);
        int byte = (r * 128 + c8 * 16) ^ ((r & 7) << 4);
        *(uint4*)((char*)sh + byte) = v;
    }
    __syncthreads();

    f32x4 acc[4] = {{0.f, 0.f, 0.f, 0.f}, {0.f, 0.f, 0.f, 0.f},
                    {0.f, 0.f, 0.f, 0.f}, {0.f, 0.f, 0.f, 0.f}};
    int ar = w * 16 + (lane & 15);
    int ak = (lane >> 4) * 8;
#pragma unroll
    for (int ks = 0; ks < 2; ++ks) {
        int byte = (ar * 128 + (ks * 32 + ak) * 2) ^ ((ar & 7) << 4);
        f16x8 af = *(const f16x8*)((const char*)sh + byte);
#pragma unroll
        for (int ct = 0; ct < 4; ++ct)
            acc[ct] = __builtin_amdgcn_mfma_f32_16x16x32_f16(af, bf[ct][ks], acc[ct], 0, 0, 0);
    }
#pragma unroll
    for (int ct = 0; ct < 4; ++ct) {
        int col = ct * 16 + (lane & 15);
#pragma unroll
        for (int r2 = 0; r2 < 4; ++r2) {
            int row = row0 + w * 16 + (lane >> 4) * 4 + r2;
            if (row < NN)
                hws[(size_t)row * NH + col] = __float2half(acc[ct][r2] * dsq[row]);
        }
    }
}

// Gather core: wave per node, 8 groups of 8 lanes; 64 edge indices loaded with
// ONE coalesced read, broadcast via shfl. Partial steps clamp to deg-1 + mask.
#define ADDROWM(sidx, m)                                                     \
    {                                                                        \
        uint4 rv = *(const uint4*)(hws_in + (size_t)(sidx) * NH + fl);       \
        float2 f0 = __half22float2(*(const __half2*)&rv.x);                  \
        float2 f1 = __half22float2(*(const __half2*)&rv.y);                  \
        float2 f2 = __half22float2(*(const __half2*)&rv.z);                  \
        float2 f3 = __half22float2(*(const __half2*)&rv.w);                  \
        a0 += f0.x * (m); a1 += f0.y * (m); a2 += f1.x * (m); a3 += f1.y * (m); \
        a4 += f2.x * (m); a5 += f2.y * (m); a6 += f3.x * (m); a7 += f3.y * (m); \
    }

#define GATHER_BODY                                                          \
    int t = threadIdx.x;                                                     \
    int node = blockIdx.x * 4 + (t >> 6);                                    \
    int lane = t & 63;                                                       \
    int g = lane >> 3;                                                       \
    int fl = (lane & 7) << 3;                                                \
    int beg = rowptr[node], end = rowptr[node + 1];                          \
    int deg = end - beg;                                                     \
    float a0 = 0.f, a1 = 0.f, a2 = 0.f, a3 = 0.f;                            \
    float a4 = 0.f, a5 = 0.f, a6 = 0.f, a7 = 0.f;                            \
    if (g == 0) ADDROWM(node, 1.f);                                          \
    int idxl = csr_src[min(beg + lane, NE - 1)];                             \
    _Pragma("unroll")                                                        \
    for (int k = 0; k < 8; ++k) {                                            \
        if (k * 8 < deg) {                                                   \
            int e = k * 8 + g;                                               \
            int s_ = __shfl(idxl, min(e, deg - 1));                          \
            float m = (e < deg) ? 1.f : 0.f;                                 \
            ADDROWM(s_, m);                                                  \
        }                                                                    \
    }                                                                        \
    for (int jb = beg + 64; jb < end; jb += 64) {  /* deg>64 fallback */     \
        int rem = end - jb;                                                  \
        int idx2 = csr_src[min(jb + lane, NE - 1)];                          \
        _Pragma("unroll")                                                    \
        for (int k = 0; k < 8; ++k) {                                        \
            if (k * 8 < rem) {                                               \
                int e = k * 8 + g;                                           \
                int s_ = __shfl(idx2, min(e, rem - 1));                      \
                float m = (e < rem) ? 1.f : 0.f;                             \
                ADDROWM(s_, m);                                              \
            }                                                                \
        }                                                                    \
    }                                                                        \
    a0 += __shfl_xor(a0, 8);  a1 += __shfl_xor(a1, 8);                       \
    a2 += __shfl_xor(a2, 8);  a3 += __shfl_xor(a3, 8);                       \
    a4 += __shfl_xor(a4, 8);  a5 += __shfl_xor(a5, 8);                       \
    a6 += __shfl_xor(a6, 8);  a7 += __shfl_xor(a7, 8);                       \
    a0 += __shfl_xor(a0, 16); a1 += __shfl_xor(a1, 16);                      \
    a2 += __shfl_xor(a2, 16); a3 += __shfl_xor(a3, 16);                      \
    a4 += __shfl_xor(a4, 16); a5 += __shfl_xor(a5, 16);                      \
    a6 += __shfl_xor(a6, 16); a7 += __shfl_xor(a7, 16);                      \
    a0 += __shfl_xor(a0, 32); a1 += __shfl_xor(a1, 32);                      \
    a2 += __shfl_xor(a2, 32); a3 += __shfl_xor(a3, 32);                      \
    a4 += __shfl_xor(a4, 32); a5 += __shfl_xor(a5, 32);                      \
    a6 += __shfl_xor(a6, 32); a7 += __shfl_xor(a7, 32);

// h = relu(dsq*(agg+self)+b), fp16 out (feeds layer_gemm)
__global__ __launch_bounds__(256) void gather_h(const int* __restrict__ rowptr,
                                                const int* __restrict__ csr_src,
                                                const __half* __restrict__ hws_in,
                                                const float* __restrict__ dsq,
                                                const float* __restrict__ b,
                                                __half* __restrict__ hout) {
    GATHER_BODY
    if (lane < 8) {
        float ds = dsq[node];
        float4 b0 = *(const float4*)(b + fl);
        float4 b1 = *(const float4*)(b + fl + 4);
        __half2 o[4];
        o[0] = __floats2half2_rn(fmaxf(ds * a0 + b0.x, 0.f), fmaxf(ds * a1 + b0.y, 0.f));
        o[1] = __floats2half2_rn(fmaxf(ds * a2 + b0.z, 0.f), fmaxf(ds * a3 + b0.w, 0.f));
        o[2] = __floats2half2_rn(fmaxf(ds * a4 + b1.x, 0.f), fmaxf(ds * a5 + b1.y, 0.f));
        o[3] = __floats2half2_rn(fmaxf(ds * a6 + b1.z, 0.f), fmaxf(ds * a7 + b1.w, 0.f));
        *(uint4*)(hout + (size_t)node * NH + fl) = *(const uint4*)o;
    }
}

// final: out = relu(dsq*(agg+self)+b), fp32
__global__ __launch_bounds__(256) void gather_out(const int* __restrict__ rowptr,
                                                  const int* __restrict__ csr_src,
                                                  const __half* __restrict__ hws_in,
                                                  const float* __restrict__ dsq,
                                                  const float* __restrict__ b,
                                                  float* __restrict__ outbuf) {
    GATHER_BODY
    if (lane < 8) {
        float ds = dsq[node];
        float4 b0 = *(const float4*)(b + fl);
        float4 b1 = *(const float4*)(b + fl + 4);
        float4 o0, o1;
        o0.x = fmaxf(ds * a0 + b0.x, 0.f);
        o0.y = fmaxf(ds * a1 + b0.y, 0.f);
        o0.z = fmaxf(ds * a2 + b0.z, 0.f);
        o0.w = fmaxf(ds * a3 + b0.w, 0.f);
        o1.x = fmaxf(ds * a4 + b1.x, 0.f);
        o1.y = fmaxf(ds * a5 + b1.y, 0.f);
        o1.z = fmaxf(ds * a6 + b1.z, 0.f);
        o1.w = fmaxf(ds * a7 + b1.w, 0.f);
        *(float4*)(outbuf + (size_t)node * NH + fl) = o0;
        *(float4*)(outbuf + (size_t)node * NH + fl + 4) = o1;
    }
}

extern "C" void kernel_launch(void* const* d_in, const int* in_sizes, int n_in,
                              void* d_out, int out_size, void* d_ws, size_t ws_size,
                              hipStream_t stream) {
    const float* x     = (const float*)d_in[0];
    const int*   ei    = (const int*)d_in[1];
    const float* W_emb = (const float*)d_in[2];
    const float* b_emb = (const float*)d_in[3];
    const float* Ws    = (const float*)d_in[4];
    const float* bs    = (const float*)d_in[5];
    float* out = (float*)d_out;

    const int* src = ei;
    const int* dst = ei + NE;

    char* w = (char*)d_ws;
    int*      bcnt    = (int*)w;              w += 256 * 4;
    int*      cbase   = (int*)w;              w += 256 * 4;
    int*      rowptr  = (int*)w;              w += (NN + 1) * 4;
    float*    dsq     = (float*)w;            w += NN * 4;
    float*    bc      = (float*)w;            w += NH * 4;
    _Float16* Wct     = (_Float16*)w;         w += NF * NH * 2;
    _Float16* Wt1     = (_Float16*)w;         w += NH * NH * 2;
    _Float16* Wt2     = (_Float16*)w;         w += NH * NH * 2;
    int*      csr_src = (int*)w;              w += NE * 4;
    int*      tmp     = (int*)w;              w += (size_t)NBUCK * CAP * 4;
    __half*   Bh      = (__half*)w;           w += (size_t)NN * NH * 2;   // hws
    __half*   H16     = (__half*)w;                                      // h

    // --- CSR build (once per call) ---
    hipMemsetAsync(bcnt, 0, 256 * 4, stream);
    part_bucket2<<<(NE + CHA - 1) / CHA, 256, 0, stream>>>(src, dst, bcnt, tmp, NE);
    scan_buckets<<<1, 256, 0, stream>>>(bcnt, cbase, rowptr);
    bucket_finalize<<<NBUCK, 256, 0, stream>>>(bcnt, cbase, tmp, rowptr, dsq, csr_src);

    // --- weight prep: fold embed into layer-0, fp16-transpose all ---
    combine_w<<<NF / 4, 256, 0, stream>>>(W_emb, b_emb, Ws, Wct, bc);
    wconv<<<16, 256, 0, stream>>>(Ws + 1 * NH * NH, Wt1);
    wconv<<<16, 256, 0, stream>>>(Ws + 2 * NH * NH, Wt2);

    // --- layer 0 GEMM (fused with embedding) ---
    fuse0_gemm<<<NBLK, 256, 0, stream>>>(x, Wct, bc, dsq, Bh);

    // --- gather -> h ; layer GEMMs ---
    gather_h<<<NN / 4, 256, 0, stream>>>(rowptr, csr_src, Bh, dsq, bs, H16);
    layer_gemm<<<NBLK, 256, 0, stream>>>(H16, Wt1, dsq, Bh);
    gather_h<<<NN / 4, 256, 0, stream>>>(rowptr, csr_src, Bh, dsq, bs + NH, H16);
    layer_gemm<<<NBLK, 256, 0, stream>>>(H16, Wt2, dsq, Bh);
    // --- final gather ---
    gather_out<<<NN / 4, 256, 0, stream>>>(rowptr, csr_src, Bh, dsq,
                                           bs + 2 * NH, out);
}

// Round 13
// 266.118 us; speedup vs baseline: 1.1685x; 1.0549x over previous
//
#include <hip/hip_runtime.h>
#include <hip/hip_fp16.h>
#include <math.h>

#define NN 100000
#define NE 1600000
#define NF 128
#define NH 64
#define NBUCK 196     // ceil(NN / 512)
#define CHA 8192      // edges per block in partition pass
#define CAP 10240     // per-bucket capacity (mean 8163, +23 sigma)
#define NBLK 1563     // ceil(NN / 64) for MFMA GEMMs

typedef _Float16 f16x8 __attribute__((ext_vector_type(8)));
typedef float f32x4 __attribute__((ext_vector_type(4)));

// Pass A: partition edges into 512-node dst-buckets (fixed-capacity regions).
// dst chunk cached in LDS so it is read from global only once.
__global__ __launch_bounds__(256) void part_bucket2(const int* __restrict__ src,
                                                    const int* __restrict__ dst,
                                                    int* __restrict__ bcnt,
                                                    int* __restrict__ tmp, int E) {
    __shared__ int hist[NBUCK];
    __shared__ int base[NBUCK];
    __shared__ int dbuf[CHA];    // 32 KB
    int t = threadIdx.x;
    int e0 = blockIdx.x * CHA;
    int n = min(CHA, E - e0);
    if (t < NBUCK) hist[t] = 0;
    __syncthreads();
    for (int i = t; i < n; i += 256) {
        int d = dst[e0 + i];
        dbuf[i] = d;
        atomicAdd(&hist[d >> 9], 1);
    }
    __syncthreads();
    if (t < NBUCK) {
        int h = hist[t];
        base[t] = h ? atomicAdd(&bcnt[t], h) : 0;
        hist[t] = 0;
    }
    __syncthreads();
    for (int i = t; i < n; i += 256) {
        int d = dbuf[i];
        int b = d >> 9;
        int r = atomicAdd(&hist[b], 1);
        tmp[b * CAP + base[b] + r] = ((d & 511) << 17) | src[e0 + i];
    }
}

// exclusive scan of the 196 bucket counts -> CSR base per bucket
__global__ __launch_bounds__(256) void scan_buckets(const int* __restrict__ bcnt,
                                                    int* __restrict__ cbase,
                                                    int* __restrict__ rowptr) {
    __shared__ int s[256];
    int t = threadIdx.x;
    s[t] = (t < NBUCK) ? bcnt[t] : 0;
    __syncthreads();
    for (int off = 1; off < 256; off <<= 1) {
        int v = (t >= off) ? s[t - off] : 0;
        __syncthreads();
        s[t] += v;
        __syncthreads();
    }
    if (t < NBUCK) cbase[t] = (t == 0) ? 0 : s[t - 1];
    if (t == 0) rowptr[NN] = NE;
}

// Pass B: one block per bucket. Stage entries in LDS, per-node degree histogram
// (-> rowptr, dsq), LDS scan, LDS-cursor scatter into csr_src.
__global__ __launch_bounds__(256) void bucket_finalize(const int* __restrict__ bcnt,
                                                       const int* __restrict__ cbase,
                                                       const int* __restrict__ tmp,
                                                       int* __restrict__ rowptr,
                                                       float* __restrict__ dsq,
                                                       int* __restrict__ csr_src) {
    __shared__ int ebuf[CAP];   // 40 KB
    __shared__ int hcnt[512];
    __shared__ int hoff[512];
    __shared__ int s[256];
    int b = blockIdx.x, t = threadIdx.x;
    int cb = bcnt[b];
    int base = cbase[b];
    const int* tsrc = tmp + b * CAP;
    for (int i = t; i < cb; i += 256) ebuf[i] = tsrc[i];
    hcnt[t] = 0;
    hcnt[t + 256] = 0;
    __syncthreads();
    for (int i = t; i < cb; i += 256) atomicAdd(&hcnt[ebuf[i] >> 17], 1);
    __syncthreads();
    int c0 = hcnt[2 * t], c1 = hcnt[2 * t + 1];
    s[t] = c0 + c1;
    __syncthreads();
    for (int off = 1; off < 256; off <<= 1) {
        int v = (t >= off) ? s[t - off] : 0;
        __syncthreads();
        s[t] += v;
        __syncthreads();
    }
    int pb = (t == 0) ? 0 : s[t - 1];
    hoff[2 * t] = pb;
    hoff[2 * t + 1] = pb + c0;
    __syncthreads();
    int nodelo = b << 9;
    int nnodes = min(512, NN - nodelo);
    for (int i = t; i < nnodes; i += 256) {
        rowptr[nodelo + i] = base + hoff[i];
        dsq[nodelo + i] = rsqrtf((float)hcnt[i] + 1.0f);
    }
    __syncthreads();
    for (int i = t; i < cb; i += 256) {
        int e = ebuf[i];
        int dlow = e >> 17;
        int p = atomicAdd(&hoff[dlow], 1);
        csr_src[base + p] = e & 0x1FFFF;
    }
}

// merged weight prep. blocks 0-31: Wct=(We@W0)^T fp16 + bc; 32-47: Wt1; 48-63: Wt2.
__global__ __launch_bounds__(256) void prep_w(const float* __restrict__ We,
                                              const float* __restrict__ be,
                                              const float* __restrict__ Ws,
                                              _Float16* __restrict__ Wct,
                                              float* __restrict__ bc,
                                              _Float16* __restrict__ Wt1,
                                              _Float16* __restrict__ Wt2) {
    int bb = blockIdx.x;
    int t = threadIdx.x;
    if (bb < 32) {
        __shared__ float w0[NH * NH];
        for (int i = t; i < NH * NH; i += 256) w0[i] = Ws[i];
        __syncthreads();
        int row = bb * 4 + (t >> 6);  // k index 0..127
        int col = t & 63;
        float a = 0.f;
#pragma unroll 8
        for (int k = 0; k < NH; ++k) a += We[row * NH + k] * w0[k * NH + col];
        Wct[col * NF + row] = (_Float16)a;
        if (bb == 0 && t < NH) {
            float s = 0.f;
            for (int k = 0; k < NH; ++k) s += be[k] * w0[k * NH + t];
            bc[t] = s;
        }
    } else {
        int which = (bb - 32) >> 4;          // 0 -> Wt1, 1 -> Wt2
        int i = ((bb - 32) & 15) * 256 + t;  // 0..4095
        int k = i >> 6, c = i & 63;
        const float* W = Ws + (which + 1) * NH * NH;
        _Float16* Wt = which ? Wt2 : Wt1;
        Wt[c * NH + k] = (_Float16)W[i];
    }
}

// hws0 = (x @ Wc + bc) * dsq[row], fp16 out. MFMA 16x16x32_f16, 64 rows/block.
__global__ __launch_bounds__(256) void fuse0_gemm(const float* __restrict__ x,
                                                  const _Float16* __restrict__ Wct,
                                                  const float* __restrict__ bc,
                                                  const float* __restrict__ dsq,
                                                  __half* __restrict__ hws) {
    __shared__ _Float16 sh[64 * NF];  // 16 KB, 256B rows, XOR-swizzled
    int t = threadIdx.x;
    int lane = t & 63;
    int w = t >> 6;
    int row0 = blockIdx.x * 64;

    f16x8 bf[4][4];
#pragma unroll
    for (int ct = 0; ct < 4; ++ct)
#pragma unroll
        for (int ks = 0; ks < 4; ++ks) {
            int col = ct * 16 + (lane & 15);
            int k = ks * 32 + (lane >> 4) * 8;
            bf[ct][ks] = *(const f16x8*)(Wct + col * NF + k);
        }

    const float4* xs = (const float4*)x;
#pragma unroll
    for (int i = 0; i < 8; ++i) {
        int f = t + i * 256;
        int r = f >> 5;
        int c4 = f & 31;
        int row = min(row0 + r, NN - 1);
        float4 v = xs[(size_t)row * 32 + c4];
        __half2 h0 = __floats2half2_rn(v.x, v.y);
        __half2 h1 = __floats2half2_rn(v.z, v.w);
        uint2 u;
        u.x = *(unsigned*)&h0;
        u.y = *(unsigned*)&h1;
        int byte = (r * 256 + c4 * 8) ^ ((r & 7) << 4);
        *(uint2*)((char*)sh + byte) = u;
    }
    __syncthreads();

    f32x4 acc[4] = {{0.f, 0.f, 0.f, 0.f}, {0.f, 0.f, 0.f, 0.f},
                    {0.f, 0.f, 0.f, 0.f}, {0.f, 0.f, 0.f, 0.f}};
    int ar = w * 16 + (lane & 15);
    int ak = (lane >> 4) * 8;
#pragma unroll
    for (int ks = 0; ks < 4; ++ks) {
        int byte = (ar * 256 + (ks * 32 + ak) * 2) ^ ((ar & 7) << 4);
        f16x8 af = *(const f16x8*)((const char*)sh + byte);
#pragma unroll
        for (int ct = 0; ct < 4; ++ct)
            acc[ct] = __builtin_amdgcn_mfma_f32_16x16x32_f16(af, bf[ct][ks], acc[ct], 0, 0, 0);
    }
#pragma unroll
    for (int ct = 0; ct < 4; ++ct) {
        int col = ct * 16 + (lane & 15);
        float bcv = bc[col];
#pragma unroll
        for (int r2 = 0; r2 < 4; ++r2) {
            int row = row0 + w * 16 + (lane >> 4) * 4 + r2;
            if (row < NN)
                hws[(size_t)row * NH + col] = __float2half((acc[ct][r2] + bcv) * dsq[row]);
        }
    }
}

// hws = (h @ W) * dsq[row], fp16 in/out. MFMA, K=64, 64 rows/block.
__global__ __launch_bounds__(256) void layer_gemm(const __half* __restrict__ h,
                                                  const _Float16* __restrict__ Wt,
                                                  const float* __restrict__ dsq,
                                                  __half* __restrict__ hws) {
    __shared__ _Float16 sh[64 * NH];  // 8 KB, 128B rows, XOR-swizzled
    int t = threadIdx.x;
    int lane = t & 63;
    int w = t >> 6;
    int row0 = blockIdx.x * 64;

    f16x8 bf[4][2];
#pragma unroll
    for (int ct = 0; ct < 4; ++ct)
#pragma unroll
        for (int ks = 0; ks < 2; ++ks) {
            int col = ct * 16 + (lane & 15);
            int k = ks * 32 + (lane >> 4) * 8;
            bf[ct][ks] = *(const f16x8*)(Wt + col * NH + k);
        }

#pragma unroll
    for (int i = 0; i < 2; ++i) {
        int u = t + i * 256;
        int r = u >> 3;
        int c8 = u & 7;
        int row = min(row0 + r, NN - 1);
        uint4 v = *(const uint4*)(h + (size_t)row * NH + c8 * 8);
        int byte = (r * 128 + c8 * 16) ^ ((r & 7) << 4);
        *(uint4*)((char*)sh + byte) = v;
    }
    __syncthreads();

    f32x4 acc[4] = {{0.f, 0.f, 0.f, 0.f}, {0.f, 0.f, 0.f, 0.f},
                    {0.f, 0.f, 0.f, 0.f}, {0.f, 0.f, 0.f, 0.f}};
    int ar = w * 16 + (lane & 15);
    int ak = (lane >> 4) * 8;
#pragma unroll
    for (int ks = 0; ks < 2; ++ks) {
        int byte = (ar * 128 + (ks * 32 + ak) * 2) ^ ((ar & 7) << 4);
        f16x8 af = *(const f16x8*)((const char*)sh + byte);
#pragma unroll
        for (int ct = 0; ct < 4; ++ct)
            acc[ct] = __builtin_amdgcn_mfma_f32_16x16x32_f16(af, bf[ct][ks], acc[ct], 0, 0, 0);
    }
#pragma unroll
    for (int ct = 0; ct < 4; ++ct) {
        int col = ct * 16 + (lane & 15);
#pragma unroll
        for (int r2 = 0; r2 < 4; ++r2) {
            int row = row0 + w * 16 + (lane >> 4) * 4 + r2;
            if (row < NN)
                hws[(size_t)row * NH + col] = __float2half(acc[ct][r2] * dsq[row]);
        }
    }
}

// Gather core: wave per node, 4 groups of 16 lanes (4 feats/lane, 8B loads).
// Edge indices: one coalesced read + shfl broadcast. Branchless masked
// super-steps of 16 edges (4 unconditional steps) -> 4 loads in flight.
#define ADDROWM(sidx, m)                                                     \
    {                                                                        \
        uint2 rv = *(const uint2*)(hws_in + (size_t)(sidx) * NH + fl);       \
        float2 f0 = __half22float2(*(const __half2*)&rv.x);                  \
        float2 f1 = __half22float2(*(const __half2*)&rv.y);                  \
        a0 += f0.x * (m); a1 += f0.y * (m);                                  \
        a2 += f1.x * (m); a3 += f1.y * (m);                                  \
    }

#define GATHER_BODY                                                          \
    int t = threadIdx.x;                                                     \
    int node = blockIdx.x * 4 + (t >> 6);                                    \
    int lane = t & 63;                                                       \
    int g = lane >> 4;            /* edge slot 0..3 */                       \
    int fl = (lane & 15) << 2;    /* feature base, 4 feats */                \
    int beg = rowptr[node], end = rowptr[node + 1];                          \
    int deg = end - beg;                                                     \
    float a0 = 0.f, a1 = 0.f, a2 = 0.f, a3 = 0.f;                            \
    if (g == 0) ADDROWM(node, 1.f);                                          \
    int idxl = csr_src[min(beg + lane, NE - 1)];                             \
    {                                                                        \
        int degc = min(deg, 64);                                             \
        int nsup = (degc + 15) >> 4;                                         \
        for (int sup = 0; sup < nsup; ++sup) {                               \
            int eb = sup * 16 + g;                                           \
            _Pragma("unroll")                                                \
            for (int q = 0; q < 4; ++q) {                                    \
                int e = eb + q * 4;                                          \
                int s_ = __shfl(idxl, min(e, degc - 1));                     \
                float m = (e < degc) ? 1.f : 0.f;                            \
                ADDROWM(s_, m);                                              \
            }                                                                \
        }                                                                    \
    }                                                                        \
    for (int jb = beg + 64; jb < end; jb += 64) {  /* deg>64 fallback */     \
        int remc = min(end - jb, 64);                                        \
        int idx2 = csr_src[min(jb + lane, NE - 1)];                          \
        int nsup = (remc + 15) >> 4;                                         \
        for (int sup = 0; sup < nsup; ++sup) {                               \
            int eb = sup * 16 + g;                                           \
            _Pragma("unroll")                                                \
            for (int q = 0; q < 4; ++q) {                                    \
                int e = eb + q * 4;                                          \
                int s_ = __shfl(idx2, min(e, remc - 1));                     \
                float m = (e < remc) ? 1.f : 0.f;                            \
                ADDROWM(s_, m);                                              \
            }                                                                \
        }                                                                    \
    }                                                                        \
    a0 += __shfl_xor(a0, 16); a1 += __shfl_xor(a1, 16);                      \
    a2 += __shfl_xor(a2, 16); a3 += __shfl_xor(a3, 16);                      \
    a0 += __shfl_xor(a0, 32); a1 += __shfl_xor(a1, 32);                      \
    a2 += __shfl_xor(a2, 32); a3 += __shfl_xor(a3, 32);

// h = relu(dsq*(agg+self)+b), fp16 out (feeds layer_gemm)
__global__ __launch_bounds__(256) void gather_h(const int* __restrict__ rowptr,
                                                const int* __restrict__ csr_src,
                                                const __half* __restrict__ hws_in,
                                                const float* __restrict__ dsq,
                                                const float* __restrict__ b,
                                                __half* __restrict__ hout) {
    GATHER_BODY
    if (lane < 16) {
        float ds = dsq[node];
        float4 b0 = *(const float4*)(b + fl);
        __half2 o0 = __floats2half2_rn(fmaxf(ds * a0 + b0.x, 0.f),
                                       fmaxf(ds * a1 + b0.y, 0.f));
        __half2 o1 = __floats2half2_rn(fmaxf(ds * a2 + b0.z, 0.f),
                                       fmaxf(ds * a3 + b0.w, 0.f));
        uint2 u;
        u.x = *(unsigned*)&o0;
        u.y = *(unsigned*)&o1;
        *(uint2*)(hout + (size_t)node * NH + fl) = u;
    }
}

// final: out = relu(dsq*(agg+self)+b), fp32
__global__ __launch_bounds__(256) void gather_out(const int* __restrict__ rowptr,
                                                  const int* __restrict__ csr_src,
                                                  const __half* __restrict__ hws_in,
                                                  const float* __restrict__ dsq,
                                                  const float* __restrict__ b,
                                                  float* __restrict__ outbuf) {
    GATHER_BODY
    if (lane < 16) {
        float ds = dsq[node];
        float4 b0 = *(const float4*)(b + fl);
        float4 o;
        o.x = fmaxf(ds * a0 + b0.x, 0.f);
        o.y = fmaxf(ds * a1 + b0.y, 0.f);
        o.z = fmaxf(ds * a2 + b0.z, 0.f);
        o.w = fmaxf(ds * a3 + b0.w, 0.f);
        *(float4*)(outbuf + (size_t)node * NH + fl) = o;
    }
}

extern "C" void kernel_launch(void* const* d_in, const int* in_sizes, int n_in,
                              void* d_out, int out_size, void* d_ws, size_t ws_size,
                              hipStream_t stream) {
    const float* x     = (const float*)d_in[0];
    const int*   ei    = (const int*)d_in[1];
    const float* W_emb = (const float*)d_in[2];
    const float* b_emb = (const float*)d_in[3];
    const float* Ws    = (const float*)d_in[4];
    const float* bs    = (const float*)d_in[5];
    float* out = (float*)d_out;

    const int* src = ei;
    const int* dst = ei + NE;

    char* w = (char*)d_ws;
    int*      bcnt    = (int*)w;              w += 256 * 4;
    int*      cbase   = (int*)w;              w += 256 * 4;
    int*      rowptr  = (int*)w;              w += (NN + 1) * 4;
    float*    dsq     = (float*)w;            w += NN * 4;
    float*    bc      = (float*)w;            w += NH * 4;
    _Float16* Wct     = (_Float16*)w;         w += NF * NH * 2;
    _Float16* Wt1     = (_Float16*)w;         w += NH * NH * 2;
    _Float16* Wt2     = (_Float16*)w;         w += NH * NH * 2;
    int*      csr_src = (int*)w;              w += NE * 4;
    int*      tmp     = (int*)w;              w += (size_t)NBUCK * CAP * 4;
    __half*   Bh      = (__half*)w;           w += (size_t)NN * NH * 2;   // hws
    __half*   H16     = (__half*)w;                                      // h

    // --- CSR build (once per call) ---
    hipMemsetAsync(bcnt, 0, 256 * 4, stream);
    part_bucket2<<<(NE + CHA - 1) / CHA, 256, 0, stream>>>(src, dst, bcnt, tmp, NE);
    scan_buckets<<<1, 256, 0, stream>>>(bcnt, cbase, rowptr);
    bucket_finalize<<<NBUCK, 256, 0, stream>>>(bcnt, cbase, tmp, rowptr, dsq, csr_src);

    // --- weight prep (merged): fold embed into layer-0, fp16-transpose all ---
    prep_w<<<64, 256, 0, stream>>>(W_emb, b_emb, Ws, Wct, bc, Wt1, Wt2);

    // --- layer 0 GEMM (fused with embedding) ---
    fuse0_gemm<<<NBLK, 256, 0, stream>>>(x, Wct, bc, dsq, Bh);

    // --- gather -> h ; layer GEMMs ---
    gather_h<<<NN / 4, 256, 0, stream>>>(rowptr, csr_src, Bh, dsq, bs, H16);
    layer_gemm<<<NBLK, 256, 0, stream>>>(H16, Wt1, dsq, Bh);
    gather_h<<<NN / 4, 256, 0, stream>>>(rowptr, csr_src, Bh, dsq, bs + NH, H16);
    layer_gemm<<<NBLK, 256, 0, stream>>>(H16, Wt2, dsq, Bh);
    // --- final gather ---
    gather_out<<<NN / 4, 256, 0, stream>>>(rowptr, csr_src, Bh, dsq,
                                           bs + 2 * NH, out);
}

// Round 15
// 264.830 us; speedup vs baseline: 1.1742x; 1.0049x over previous
//
#include <hip/hip_runtime.h>
#include <hip/hip_fp16.h>
#include <math.h>

#define NN 100000
#define NE 1600000
#define NF 128
#define NH 64
#define NBUCK 196     // ceil(NN / 512)
#define CHA 8192      // edges per block in partition pass
#define CAP 10240     // per-bucket capacity (mean 8163, +23 sigma)
#define NBLK 1563     // ceil(NN / 64) for MFMA GEMMs

typedef _Float16 f16x8 __attribute__((ext_vector_type(8)));
typedef float f32x4 __attribute__((ext_vector_type(4)));

// Pass A: partition edges into 512-node dst-buckets (fixed-capacity regions).
// dst chunk cached in LDS so it is read from global only once.
__global__ __launch_bounds__(256) void part_bucket2(const int* __restrict__ src,
                                                    const int* __restrict__ dst,
                                                    int* __restrict__ bcnt,
                                                    int* __restrict__ tmp, int E) {
    __shared__ int hist[NBUCK];
    __shared__ int base[NBUCK];
    __shared__ int dbuf[CHA];    // 32 KB
    int t = threadIdx.x;
    int e0 = blockIdx.x * CHA;
    int n = min(CHA, E - e0);
    if (t < NBUCK) hist[t] = 0;
    __syncthreads();
    for (int i = t; i < n; i += 256) {
        int d = dst[e0 + i];
        dbuf[i] = d;
        atomicAdd(&hist[d >> 9], 1);
    }
    __syncthreads();
    if (t < NBUCK) {
        int h = hist[t];
        base[t] = h ? atomicAdd(&bcnt[t], h) : 0;
        hist[t] = 0;
    }
    __syncthreads();
    for (int i = t; i < n; i += 256) {
        int d = dbuf[i];
        int b = d >> 9;
        int r = atomicAdd(&hist[b], 1);
        tmp[b * CAP + base[b] + r] = ((d & 511) << 17) | src[e0 + i];
    }
}

// Pass B: one block per bucket. Re-derives its CSR base from bcnt (local scan),
// stages entries in LDS, per-node degree histogram (-> rowptr, dsq), LDS scan,
// LDS-cursor scatter into csr_src.
__global__ __launch_bounds__(256) void bucket_finalize(const int* __restrict__ bcnt,
                                                       const int* __restrict__ tmp,
                                                       int* __restrict__ rowptr,
                                                       float* __restrict__ dsq,
                                                       int* __restrict__ csr_src) {
    __shared__ int ebuf[CAP];   // 40 KB
    __shared__ int hcnt[512];
    __shared__ int hoff[512];
    __shared__ int s[256];
    int b = blockIdx.x, t = threadIdx.x;

    // local exclusive scan of bcnt -> this bucket's CSR base
    s[t] = (t < NBUCK) ? bcnt[t] : 0;
    __syncthreads();
    for (int off = 1; off < 256; off <<= 1) {
        int v = (t >= off) ? s[t - off] : 0;
        __syncthreads();
        s[t] += v;
        __syncthreads();
    }
    int base = (b == 0) ? 0 : s[b - 1];
    int cb = bcnt[b];
    if (b == 0 && t == 0) rowptr[NN] = NE;
    __syncthreads();

    const int* tsrc = tmp + b * CAP;
    for (int i = t; i < cb; i += 256) ebuf[i] = tsrc[i];
    hcnt[t] = 0;
    hcnt[t + 256] = 0;
    __syncthreads();
    for (int i = t; i < cb; i += 256) atomicAdd(&hcnt[ebuf[i] >> 17], 1);
    __syncthreads();
    int c0 = hcnt[2 * t], c1 = hcnt[2 * t + 1];
    s[t] = c0 + c1;
    __syncthreads();
    for (int off = 1; off < 256; off <<= 1) {
        int v = (t >= off) ? s[t - off] : 0;
        __syncthreads();
        s[t] += v;
        __syncthreads();
    }
    int pb = (t == 0) ? 0 : s[t - 1];
    hoff[2 * t] = pb;
    hoff[2 * t + 1] = pb + c0;
    __syncthreads();
    int nodelo = b << 9;
    int nnodes = min(512, NN - nodelo);
    for (int i = t; i < nnodes; i += 256) {
        rowptr[nodelo + i] = base + hoff[i];
        dsq[nodelo + i] = rsqrtf((float)hcnt[i] + 1.0f);
    }
    __syncthreads();
    for (int i = t; i < cb; i += 256) {
        int e = ebuf[i];
        int dlow = e >> 17;
        int p = atomicAdd(&hoff[dlow], 1);
        csr_src[base + p] = e & 0x1FFFF;
    }
}

// merged weight prep. blocks 0-31: Wct=(We@W0)^T fp16 + bc; 32-47: Wt1; 48-63: Wt2.
__global__ __launch_bounds__(256) void prep_w(const float* __restrict__ We,
                                              const float* __restrict__ be,
                                              const float* __restrict__ Ws,
                                              _Float16* __restrict__ Wct,
                                              float* __restrict__ bc,
                                              _Float16* __restrict__ Wt1,
                                              _Float16* __restrict__ Wt2) {
    int bb = blockIdx.x;
    int t = threadIdx.x;
    if (bb < 32) {
        __shared__ float w0[NH * NH];
        for (int i = t; i < NH * NH; i += 256) w0[i] = Ws[i];
        __syncthreads();
        int row = bb * 4 + (t >> 6);  // k index 0..127
        int col = t & 63;
        float a = 0.f;
#pragma unroll 8
        for (int k = 0; k < NH; ++k) a += We[row * NH + k] * w0[k * NH + col];
        Wct[col * NF + row] = (_Float16)a;
        if (bb == 0 && t < NH) {
            float s = 0.f;
            for (int k = 0; k < NH; ++k) s += be[k] * w0[k * NH + t];
            bc[t] = s;
        }
    } else {
        int which = (bb - 32) >> 4;          // 0 -> Wt1, 1 -> Wt2
        int i = ((bb - 32) & 15) * 256 + t;  // 0..4095
        int k = i >> 6, c = i & 63;
        const float* W = Ws + (which + 1) * NH * NH;
        _Float16* Wt = which ? Wt2 : Wt1;
        Wt[c * NH + k] = (_Float16)W[i];
    }
}

// hws0 = (x @ Wc + bc) * dsq[row], fp16 out. MFMA 16x16x32_f16, 64 rows/block.
__global__ __launch_bounds__(256) void fuse0_gemm(const float* __restrict__ x,
                                                  const _Float16* __restrict__ Wct,
                                                  const float* __restrict__ bc,
                                                  const float* __restrict__ dsq,
                                                  __half* __restrict__ hws) {
    __shared__ _Float16 sh[64 * NF];  // 16 KB, 256B rows, XOR-swizzled
    int t = threadIdx.x;
    int lane = t & 63;
    int w = t >> 6;
    int row0 = blockIdx.x * 64;

    f16x8 bf[4][4];
#pragma unroll
    for (int ct = 0; ct < 4; ++ct)
#pragma unroll
        for (int ks = 0; ks < 4; ++ks) {
            int col = ct * 16 + (lane & 15);
            int k = ks * 32 + (lane >> 4) * 8;
            bf[ct][ks] = *(const f16x8*)(Wct + col * NF + k);
        }

    const float4* xs = (const float4*)x;
#pragma unroll
    for (int i = 0; i < 8; ++i) {
        int f = t + i * 256;
        int r = f >> 5;
        int c4 = f & 31;
        int row = min(row0 + r, NN - 1);
        float4 v = xs[(size_t)row * 32 + c4];
        __half2 h0 = __floats2half2_rn(v.x, v.y);
        __half2 h1 = __floats2half2_rn(v.z, v.w);
        uint2 u;
        u.x = *(unsigned*)&h0;
        u.y = *(unsigned*)&h1;
        int byte = (r * 256 + c4 * 8) ^ ((r & 7) << 4);
        *(uint2*)((char*)sh + byte) = u;
    }
    __syncthreads();

    f32x4 acc[4] = {{0.f, 0.f, 0.f, 0.f}, {0.f, 0.f, 0.f, 0.f},
                    {0.f, 0.f, 0.f, 0.f}, {0.f, 0.f, 0.f, 0.f}};
    int ar = w * 16 + (lane & 15);
    int ak = (lane >> 4) * 8;
#pragma unroll
    for (int ks = 0; ks < 4; ++ks) {
        int byte = (ar * 256 + (ks * 32 + ak) * 2) ^ ((ar & 7) << 4);
        f16x8 af = *(const f16x8*)((const char*)sh + byte);
#pragma unroll
        for (int ct = 0; ct < 4; ++ct)
            acc[ct] = __builtin_amdgcn_mfma_f32_16x16x32_f16(af, bf[ct][ks], acc[ct], 0, 0, 0);
    }
#pragma unroll
    for (int ct = 0; ct < 4; ++ct) {
        int col = ct * 16 + (lane & 15);
        float bcv = bc[col];
#pragma unroll
        for (int r2 = 0; r2 < 4; ++r2) {
            int row = row0 + w * 16 + (lane >> 4) * 4 + r2;
            if (row < NN)
                hws[(size_t)row * NH + col] = __float2half((acc[ct][r2] + bcv) * dsq[row]);
        }
    }
}

// hws = (h @ W) * dsq[row], fp16 in/out. MFMA, K=64, 64 rows/block.
__global__ __launch_bounds__(256) void layer_gemm(const __half* __restrict__ h,
                                                  const _Float16* __restrict__ Wt,
                                                  const float* __restrict__ dsq,
                                                  __half* __restrict__ hws) {
    __shared__ _Float16 sh[64 * NH];  // 8 KB, 128B rows, XOR-swizzled
    int t = threadIdx.x;
    int lane = t & 63;
    int w = t >> 6;
    int row0 = blockIdx.x * 64;

    f16x8 bf[4][2];
#pragma unroll
    for (int ct = 0; ct < 4; ++ct)
#pragma unroll
        for (int ks = 0; ks < 2; ++ks) {
            int col = ct * 16 + (lane & 15);
            int k = ks * 32 + (lane >> 4) * 8;
            bf[ct][ks] = *(const f16x8*)(Wt + col * NH + k);
        }

#pragma unroll
    for (int i = 0; i < 2; ++i) {
        int u = t + i * 256;
        int r = u >> 3;
        int c8 = u & 7;
        int row = min(row0 + r, NN - 1);
        uint4 v = *(const uint4*)(h + (size_t)row * NH + c8 * 8);
        int byte = (r * 128 + c8 * 16) ^ ((r & 7) << 4);
        *(uint4*)((char*)sh + byte) = v;
    }
    __syncthreads();

    f32x4 acc[4] = {{0.f, 0.f, 0.f, 0.f}, {0.f, 0.f, 0.f, 0.f},
                    {0.f, 0.f, 0.f, 0.f}, {0.f, 0.f, 0.f, 0.f}};
    int ar = w * 16 + (lane & 15);
    int ak = (lane >> 4) * 8;
#pragma unroll
    for (int ks = 0; ks < 2; ++ks) {
        int byte = (ar * 128 + (ks * 32 + ak) * 2) ^ ((ar & 7) << 4);
        f16x8 af = *(const f16x8*)((const char*)sh + byte);
#pragma unroll
        for (int ct = 0; ct < 4; ++ct)
            acc[ct] = __builtin_amdgcn_mfma_f32_16x16x32_f16(af, bf[ct][ks], acc[ct], 0, 0, 0);
    }
#pragma unroll
    for (int ct = 0; ct < 4; ++ct) {
        int col = ct * 16 + (lane & 15);
#pragma unroll
        for (int r2 = 0; r2 < 4; ++r2) {
            int row = row0 + w * 16 + (lane >> 4) * 4 + r2;
            if (row < NN)
                hws[(size_t)row * NH + col] = __float2half(acc[ct][r2] * dsq[row]);
        }
    }
}

// Gather core (R13-proven): wave per node, 4 groups of 16 lanes (4 feats/lane,
// 8B loads). Edge indices: one coalesced read + shfl broadcast. Branchless
// masked super-steps of 16 edges (clamp index + x{0,1} mask).
#define ADDROWM(sidx, m)                                                     \
    {                                                                        \
        uint2 rv = *(const uint2*)(hws_in + (size_t)(sidx) * NH + fl);       \
        float2 f0 = __half22float2(*(const __half2*)&rv.x);                  \
        float2 f1 = __half22float2(*(const __half2*)&rv.y);                  \
        a0 += f0.x * (m); a1 += f0.y * (m);                                  \
        a2 += f1.x * (m); a3 += f1.y * (m);                                  \
    }

#define GATHER_BODY                                                          \
    int t = threadIdx.x;                                                     \
    int node = blockIdx.x * 4 + (t >> 6);                                    \
    int lane = t & 63;                                                       \
    int g = lane >> 4;            /* edge slot 0..3 */                       \
    int fl = (lane & 15) << 2;    /* feature base, 4 feats */                \
    int beg = rowptr[node], end = rowptr[node + 1];                          \
    int deg = end - beg;                                                     \
    float a0 = 0.f, a1 = 0.f, a2 = 0.f, a3 = 0.f;                            \
    if (g == 0) ADDROWM(node, 1.f);                                          \
    int idxl = csr_src[min(beg + lane, NE - 1)];                             \
    {                                                                        \
        int degc = min(deg, 64);                                             \
        int nsup = (degc + 15) >> 4;                                         \
        for (int sup = 0; sup < nsup; ++sup) {                               \
            int eb = sup * 16 + g;                                           \
            _Pragma("unroll")                                                \
            for (int q = 0; q < 4; ++q) {                                    \
                int e = eb + q * 4;                                          \
                int s_ = __shfl(idxl, min(e, degc - 1));                     \
                float m = (e < degc) ? 1.f : 0.f;                            \
                ADDROWM(s_, m);                                              \
            }                                                                \
        }                                                                    \
    }                                                                        \
    for (int jb = beg + 64; jb < end; jb += 64) {  /* deg>64 fallback */     \
        int remc = min(end - jb, 64);                                        \
        int idx2 = csr_src[min(jb + lane, NE - 1)];                          \
        int nsup = (remc + 15) >> 4;                                         \
        for (int sup = 0; sup < nsup; ++sup) {                               \
            int eb = sup * 16 + g;                                           \
            _Pragma("unroll")                                                \
            for (int q = 0; q < 4; ++q) {                                    \
                int e = eb + q * 4;                                          \
                int s_ = __shfl(idx2, min(e, remc - 1));                     \
                float m = (e < remc) ? 1.f : 0.f;                            \
                ADDROWM(s_, m);                                              \
            }                                                                \
        }                                                                    \
    }                                                                        \
    a0 += __shfl_xor(a0, 16); a1 += __shfl_xor(a1, 16);                      \
    a2 += __shfl_xor(a2, 16); a3 += __shfl_xor(a3, 16);                      \
    a0 += __shfl_xor(a0, 32); a1 += __shfl_xor(a1, 32);                      \
    a2 += __shfl_xor(a2, 32); a3 += __shfl_xor(a3, 32);

// h = relu(dsq*(agg+self)+b), fp16 out (feeds layer_gemm)
__global__ __launch_bounds__(256) void gather_h(const int* __restrict__ rowptr,
                                                const int* __restrict__ csr_src,
                                                const __half* __restrict__ hws_in,
                                                const float* __restrict__ dsq,
                                                const float* __restrict__ b,
                                                __half* __restrict__ hout) {
    GATHER_BODY
    if (lane < 16) {
        float ds = dsq[node];
        float4 b0 = *(const float4*)(b + fl);
        __half2 o0 = __floats2half2_rn(fmaxf(ds * a0 + b0.x, 0.f),
                                       fmaxf(ds * a1 + b0.y, 0.f));
        __half2 o1 = __floats2half2_rn(fmaxf(ds * a2 + b0.z, 0.f),
                                       fmaxf(ds * a3 + b0.w, 0.f));
        uint2 u;
        u.x = *(unsigned*)&o0;
        u.y = *(unsigned*)&o1;
        *(uint2*)(hout + (size_t)node * NH + fl) = u;
    }
}

// final: out = relu(dsq*(agg+self)+b), fp32
__global__ __launch_bounds__(256) void gather_out(const int* __restrict__ rowptr,
                                                  const int* __restrict__ csr_src,
                                                  const __half* __restrict__ hws_in,
                                                  const float* __restrict__ dsq,
                                                  const float* __restrict__ b,
                                                  float* __restrict__ outbuf) {
    GATHER_BODY
    if (lane < 16) {
        float ds = dsq[node];
        float4 b0 = *(const float4*)(b + fl);
        float4 o;
        o.x = fmaxf(ds * a0 + b0.x, 0.f);
        o.y = fmaxf(ds * a1 + b0.y, 0.f);
        o.z = fmaxf(ds * a2 + b0.z, 0.f);
        o.w = fmaxf(ds * a3 + b0.w, 0.f);
        *(float4*)(outbuf + (size_t)node * NH + fl) = o;
    }
}

extern "C" void kernel_launch(void* const* d_in, const int* in_sizes, int n_in,
                              void* d_out, int out_size, void* d_ws, size_t ws_size,
                              hipStream_t stream) {
    const float* x     = (const float*)d_in[0];
    const int*   ei    = (const int*)d_in[1];
    const float* W_emb = (const float*)d_in[2];
    const float* b_emb = (const float*)d_in[3];
    const float* Ws    = (const float*)d_in[4];
    const float* bs    = (const float*)d_in[5];
    float* out = (float*)d_out;

    const int* src = ei;
    const int* dst = ei + NE;

    char* w = (char*)d_ws;
    int*      bcnt    = (int*)w;              w += 256 * 4;
    int*      rowptr  = (int*)w;              w += (NN + 1) * 4;
    float*    dsq     = (float*)w;            w += NN * 4;
    float*    bc      = (float*)w;            w += NH * 4;
    _Float16* Wct     = (_Float16*)w;         w += NF * NH * 2;
    _Float16* Wt1     = (_Float16*)w;         w += NH * NH * 2;
    _Float16* Wt2     = (_Float16*)w;         w += NH * NH * 2;
    int*      csr_src = (int*)w;              w += NE * 4;
    int*      tmp     = (int*)w;              w += (size_t)NBUCK * CAP * 4;
    __half*   Bh      = (__half*)w;           w += (size_t)NN * NH * 2;   // hws
    __half*   H16     = (__half*)w;                                      // h

    // --- CSR build (once per call) ---
    hipMemsetAsync(bcnt, 0, 256 * 4, stream);
    part_bucket2<<<(NE + CHA - 1) / CHA, 256, 0, stream>>>(src, dst, bcnt, tmp, NE);
    bucket_finalize<<<NBUCK, 256, 0, stream>>>(bcnt, tmp, rowptr, dsq, csr_src);

    // --- weight prep (merged): fold embed into layer-0, fp16-transpose all ---
    prep_w<<<64, 256, 0, stream>>>(W_emb, b_emb, Ws, Wct, bc, Wt1, Wt2);

    // --- layer 0 GEMM (fused with embedding) ---
    fuse0_gemm<<<NBLK, 256, 0, stream>>>(x, Wct, bc, dsq, Bh);

    // --- gather -> h ; layer GEMMs ---
    gather_h<<<NN / 4, 256, 0, stream>>>(rowptr, csr_src, Bh, dsq, bs, H16);
    layer_gemm<<<NBLK, 256, 0, stream>>>(H16, Wt1, dsq, Bh);
    gather_h<<<NN / 4, 256, 0, stream>>>(rowptr, csr_src, Bh, dsq, bs + NH, H16);
    layer_gemm<<<NBLK, 256, 0, stream>>>(H16, Wt2, dsq, Bh);
    // --- final gather ---
    gather_out<<<NN / 4, 256, 0, stream>>>(rowptr, csr_src, Bh, dsq,
                                           bs + 2 * NH, out);
}